// Round 8
// baseline (196.839 us; speedup 1.0000x reference)
//
#include <hip/hip_runtime.h>

// RNN-T loss forward: B=8, T=128, U=100, V=1024, BLANK=0.
// INSTRUMENTATION ROUND: dp_kernel launched 4x (identical work; #2-4 write a
// dummy ws slot) to measure D_dp = (total - prev_total - launch_overhead)/3.
// Everything else is byte-identical to round 7.

#define NEGV (-1e30f)

constexpr int Bb = 8;
constexpr int Tt = 128;
constexpr int Uu = 100;
constexpr int Vv = 1024;
constexpr int UP1 = Uu + 1;
constexpr int DROWS = 244;       // staging rows (d up to 232 + lane spill)
constexpr int DPAD  = 104;       // staging row pitch in floats
constexpr int CHUNK = 8;         // diagonals per chunk
constexpr int LPITCH = 128;      // LDS row pitch in floats

__device__ __forceinline__ float laddexp(float x, float y) {
    float m = fmaxf(x, y);
    float d = fabsf(x - y);
    return m + __logf(1.0f + __expf(-d));
}

// lane l receives lane l-1's value; lane 0 -> 0
__device__ __forceinline__ float wave_shr1(float x) {
    return __builtin_bit_cast(float, __builtin_amdgcn_update_dpp(
        0, __builtin_bit_cast(int, x), 0x138, 0xf, 0xf, true));
}

__device__ __forceinline__ float readlane_f(float x, int lane) {
    return __builtin_bit_cast(float,
        __builtin_amdgcn_readlane(__builtin_bit_cast(int, x), lane));
}

// Kernel 1: per (b,t,u) row of V=1024 logits compute lse; scatter the two
// needed log-probs into diagonal-major staging:
//   bS[b][d][u]   = blank_lp[t][u] at d = t+u+1  (cell (d,u) reads blank[t-1][u])
//   eS[b][d][u+1] = emit_lp [t][u] at d = t+u+1  (cell (d,u') reads emit[t][u'-1])
__global__ __launch_bounds__(256) void lse_kernel(
        const float* __restrict__ logits,
        const int*   __restrict__ targets,
        float* __restrict__ bS,
        float* __restrict__ eS) {
    const int wid  = blockIdx.x * 4 + (threadIdx.x >> 6);   // row index
    const int lane = threadIdx.x & 63;
    const int b   = wid / (Tt * UP1);
    const int rem = wid - b * (Tt * UP1);
    const int t   = rem / UP1;
    const int u   = rem - t * UP1;

    const float* row = logits + (size_t)wid * Vv;
    const float4* r4 = (const float4*)row;
    float4 x0 = r4[lane];
    float4 x1 = r4[lane + 64];
    float4 x2 = r4[lane + 128];
    float4 x3 = r4[lane + 192];

    float m = fmaxf(fmaxf(fmaxf(x0.x, x0.y), fmaxf(x0.z, x0.w)),
                    fmaxf(fmaxf(x1.x, x1.y), fmaxf(x1.z, x1.w)));
    m = fmaxf(m, fmaxf(fmaxf(fmaxf(x2.x, x2.y), fmaxf(x2.z, x2.w)),
                       fmaxf(fmaxf(x3.x, x3.y), fmaxf(x3.z, x3.w))));
    #pragma unroll
    for (int d = 32; d > 0; d >>= 1) m = fmaxf(m, __shfl_xor(m, d, 64));

    float s = __expf(x0.x - m) + __expf(x0.y - m) + __expf(x0.z - m) + __expf(x0.w - m)
            + __expf(x1.x - m) + __expf(x1.y - m) + __expf(x1.z - m) + __expf(x1.w - m)
            + __expf(x2.x - m) + __expf(x2.y - m) + __expf(x2.z - m) + __expf(x2.w - m)
            + __expf(x3.x - m) + __expf(x3.y - m) + __expf(x3.z - m) + __expf(x3.w - m);
    #pragma unroll
    for (int d = 32; d > 0; d >>= 1) s += __shfl_xor(s, d, 64);

    float lse = m + __logf(s);

    if (lane == 0) {
        const int dw = t + u + 1;                       // 1..228
        bS[((size_t)b * DROWS + dw) * DPAD + u] = x0.x - lse;   // row[0] = BLANK
        if (u < Uu) {
            int tgt = targets[b * Uu + u];
            eS[((size_t)b * DROWS + dw) * DPAD + (u + 1)] = row[tgt] - lse;
        }
    }
}

// Kernel 2: one 128-thread block per batch. Wave 0 = DP consumer (from LDS),
// wave 1 = producer (global -> LDS double-buffer, 2 register sets deep).
__global__ __launch_bounds__(128) void dp_kernel(
        const float* __restrict__ bS,
        const float* __restrict__ eS,
        const int*   __restrict__ logit_lengths,
        const int*   __restrict__ target_lengths,
        float* __restrict__ nll) {
    const int b    = blockIdx.x;
    const int tid  = threadIdx.x;
    const int wv   = tid >> 6;          // 0 = consumer, 1 = producer
    const int lane = tid & 63;
    const float* bB = bS + (size_t)b * DROWS * DPAD;
    const float* eB = eS + (size_t)b * DROWS * DPAD;
    const int tl = logit_lengths[b];
    const int ul = target_lengths[b];
    const int t_idx = tl - 2;           // reference reads alpha[tl-2][ul]
    const int dcap  = t_idx + ul;       // diagonal of the readout cell

    __shared__ float ringB[2][CHUNK][LPITCH];
    __shared__ float ringE[2][CHUNK][LPITCH];

    // consumer state
    const int u0 = lane * 2, u1 = u0 + 1;
    float aP0 = (lane == 0) ? 0.0f : NEGV;   // alpha diag 0: only (0,0)=0
    float aP1 = NEGV;
    float cap = (dcap == 0) ? 0.0f : NEGV;

    // producer state: two register sets (chunk k lives in set k&1)
    float2 LAb[CHUNK], LAe[CHUNK], LBb[CHUNK], LBe[CHUNK];

#define PLOAD(SETb, SETe, ck) do {                                           \
        const float* _pb = bB + (size_t)((ck) * CHUNK + 1) * DPAD + lane * 2;\
        const float* _pe = eB + (size_t)((ck) * CHUNK + 1) * DPAD + lane * 2;\
        _Pragma("unroll")                                                    \
        for (int r = 0; r < CHUNK; ++r) {                                    \
            SETb[r] = *(const float2*)(_pb + r * DPAD);                      \
            SETe[r] = *(const float2*)(_pe + r * DPAD);                      \
        }                                                                    \
    } while (0)

#define PWRITE(SETb, SETe, slot) do {                                        \
        _Pragma("unroll")                                                    \
        for (int r = 0; r < CHUNK; ++r) {                                    \
            *(float2*)&ringB[slot][r][lane * 2] = SETb[r];                   \
            *(float2*)&ringE[slot][r][lane * 2] = SETe[r];                   \
        }                                                                    \
    } while (0)

    // consumer: process chunk cc from LDS slot; diagonals cc*8+1 .. cc*8+8
#define CCHUNK(cc, slot) do {                                                \
        float2 Bv[CHUNK], Ev[CHUNK];                                         \
        _Pragma("unroll")                                                    \
        for (int r = 0; r < CHUNK; ++r) {                                    \
            Bv[r] = *(const float2*)&ringB[slot][r][u0];                     \
            Ev[r] = *(const float2*)&ringE[slot][r][u0];                     \
        }                                                                    \
        _Pragma("unroll")                                                    \
        for (int r = 0; r < CHUNK; ++r) {                                    \
            const int dv = (cc) * CHUNK + 1 + r;                             \
            float sh  = wave_shr1(aP1);                                      \
            float t1b = (u1 < dv) ? aP1 + Bv[r].y : NEGV;                    \
            float t1e = aP0 + Ev[r].y;                                       \
            float t0b = (u0 < dv) ? aP0 + Bv[r].x : NEGV;                    \
            float t0e = (lane >= 1) ? sh + Ev[r].x : NEGV;                   \
            float n1 = laddexp(t1b, t1e);                                    \
            float n0 = laddexp(t0b, t0e);                                    \
            aP0 = n0; aP1 = n1;                                              \
            if (dv == dcap) {                                                \
                float w0 = readlane_f(n0, ul >> 1);                          \
                float w1 = readlane_f(n1, ul >> 1);                          \
                cap = (ul & 1) ? w1 : w0;                                    \
            }                                                                \
        }                                                                    \
    } while (0)

    // prologue: producer loads chunks 0,1 and writes chunk 0 to slot 0
    if (wv == 1) {
        PLOAD(LAb, LAe, 0);
        PLOAD(LBb, LBe, 1);
        PWRITE(LAb, LAe, 0);
    }
    __syncthreads();

    // main: 14 x (even half, odd half); consumer handles chunks 0..27
    for (int c2 = 0; c2 < 14; ++c2) {
        const int c = c2 * 2;
        if (wv == 1) {
            PLOAD(LAb, LAe, c + 2);
            PWRITE(LBb, LBe, 1);
        } else {
            CCHUNK(c, 0);
        }
        __syncthreads();
        if (wv == 1) {
            if (c2 < 13) PLOAD(LBb, LBe, c + 3);
            PWRITE(LAb, LAe, 0);
        } else {
            CCHUNK(c + 1, 1);
        }
        __syncthreads();
    }
    // final chunk 28 (slot 0), consumer only
    if (wv == 0) {
        CCHUNK(28, 0);
        if (lane == 0) {
            float ll = cap + bB[(size_t)(dcap + 1) * DPAD + ul]; // + blank[t_idx][ul]
            nll[b] = -ll;
        }
    }
#undef PLOAD
#undef PWRITE
#undef CCHUNK
}

__global__ void mean_kernel(const float* __restrict__ nll, float* __restrict__ out) {
    if (threadIdx.x == 0 && blockIdx.x == 0) {
        float s = 0.0f;
        for (int i = 0; i < Bb; ++i) s += nll[i];
        out[0] = s / (float)Bb;
    }
}

extern "C" void kernel_launch(void* const* d_in, const int* in_sizes, int n_in,
                              void* d_out, int out_size, void* d_ws, size_t ws_size,
                              hipStream_t stream) {
    const float* logits         = (const float*)d_in[0];
    const int*   targets        = (const int*)d_in[1];
    const int*   logit_lengths  = (const int*)d_in[2];
    const int*   target_lengths = (const int*)d_in[3];
    float* out = (float*)d_out;

    float* ws   = (float*)d_ws;
    float* bS   = ws;                                   // 8*244*104 floats
    float* eS   = bS + (size_t)Bb * DROWS * DPAD;
    float* nll  = eS + (size_t)Bb * DROWS * DPAD;       // 8 floats (real)
    float* nllX = nll + 8;                              // 8 floats (dummy)

    const int rows = Bb * Tt * UP1;                     // 103424, divisible by 4
    lse_kernel<<<rows / 4, 256, 0, stream>>>(logits, targets, bS, eS);
    // dp x4: #1 is the real one, #2-4 are timing probes writing to a dummy.
    dp_kernel<<<Bb, 128, 0, stream>>>(bS, eS, logit_lengths, target_lengths, nll);
    dp_kernel<<<Bb, 128, 0, stream>>>(bS, eS, logit_lengths, target_lengths, nllX);
    dp_kernel<<<Bb, 128, 0, stream>>>(bS, eS, logit_lengths, target_lengths, nllX);
    dp_kernel<<<Bb, 128, 0, stream>>>(bS, eS, logit_lengths, target_lengths, nllX);
    mean_kernel<<<1, 64, 0, stream>>>(nll, out);
}